// Round 1
// 651.350 us; speedup vs baseline: 1.0066x; 1.0066x over previous
//
#include <hip/hip_runtime.h>

// HEALPix pad, p=1, H=W=256, layout [B,12,C,H,W] -> [B,12,C,258,258].
// Setup fixed: B=2, C=64, pad=1, channels_last=False.
//
// R3: same structure as R2 (one fused kernel; each block stages a contiguous
// 16B-aligned span of one output plane through LDS, stores are aligned
// global_store_dwordx4), but the interior global LOADS are now float4
// (global_load_dwordx4, 1KB/wave-instr) instead of scalar dwords
// (256B/wave-instr). LDS staging writes become 4x ds_write_b32 at an
// 8-lanes/bank pattern (~2.9x conflict, m136) -- LDS is not the critical
// path (needs ~2x per-CU HBM rate; conflicted b32 writes still deliver it).

#define HH 256
#define HP 258
#define FACE_ELEMS (HH * HH)     // 65536
#define OFACE_ELEMS (HP * HP)    // 66564
#define NCH 64                   // channels per face (setup-fixed)

// rot90 semantics used to resolve rotated neighbors to direct source indices:
//   rot(g, 1)[y,x] = g[x,   W-1-y]
//   rot(g, 2)[y,x] = g[H-1-y, W-1-x]
//   rot(g,-1)[y,x] = g[H-1-x, y]
// This decision tree passed absmax=0 in rounds 1-2 -- kept verbatim.
__device__ __forceinline__ float halo_val(const float* __restrict__ in,
                                          int pi, int face, int oy, int ox) {
    const int i = face & 3;
    const int type = face >> 2;   // 0 north, 1 equatorial, 2 south
    const bool top = (oy == 0), bot = (oy == HP - 1);
    const bool lft = (ox == 0), rgt = (ox == HP - 1);
    const int iy = oy - 1, ix = ox - 1;

    auto src = [&](int nf, int sy, int sx) -> float {
        return in[(size_t)(pi + (nf - face) * NCH) * FACE_ELEMS + sy * HH + sx];
    };

    float val;
    if (top && lft) {                              // TL corner
        if (type == 0)      val = src((i + 2) & 3, 0, 0);                 // rot2[255,255]
        else if (type == 1) val = 0.5f * (src(i, HH - 1, 0) +
                                          src((i + 3) & 3, 0, HH - 1));   // tri-point
        else                val = src(i, HH - 1, HH - 1);
    } else if (top && rgt) {                       // TR corner
        if (type == 0)      val = src((i + 1) & 3, HH - 1, HH - 1);       // rot-1[255,0]
        else if (type == 1) val = src((i + 1) & 3, HH - 1, 0);
        else                val = src(((i + 1) & 3) + 4, HH - 1, 0);
    } else if (bot && lft) {                       // BL corner
        if (type == 0)      val = src((i + 3) & 3, 0, HH - 1);
        else if (type == 1) val = src(((i + 3) & 3) + 4, 0, HH - 1);
        else                val = src(((i + 3) & 3) + 8, 0, 0);           // rot-1[0,255]
    } else if (bot && rgt) {                       // BR corner
        if (type == 0)      val = src(i + 8, 0, 0);
        else if (type == 1) val = 0.5f * (src(i + 8, 0, HH - 1) +
                                          src(((i + 1) & 3) + 4, HH - 1, 0)); // tri-point
        else                val = src(((i + 3) & 3) + 8, HH - 1, HH - 1); // rot2[0,0]
    } else if (top) {                              // top edge
        if (type == 0)      val = src((i + 1) & 3, ix, 0);                // rot1[255,ix]
        else if (type == 1) val = src(i, HH - 1, ix);
        else                val = src(i + 4, HH - 1, ix);
    } else if (bot) {                              // bottom edge
        if (type == 0)      val = src(i + 4, 0, ix);
        else if (type == 1) val = src(i + 8, 0, ix);
        else                val = src(((i + 3) & 3) + 8, ix, HH - 1);     // rot1[0,ix]
    } else if (lft) {                              // left edge
        if (type == 2)      val = src(((i + 3) & 3) + 4, iy, HH - 1);
        else                val = src((i + 3) & 3, iy, HH - 1);
    } else {                                       // right edge
        if (type == 2)      val = src(((i + 1) & 3) + 8, iy, 0);
        else                val = src(((i + 1) & 3) + 4, iy, 0);
    }
    return val;
}

// Grid: (17, P). Block b<16 covers output rows [16b, 16b+16); block 16 covers
// rows [256, 258). The covered span is contiguous in the plane and its start
// (4128*b floats, or 66048) is a multiple of 4 floats -> 16B-aligned stores.
__global__ __launch_bounds__(256)
void healpix_fused(const float* __restrict__ in, float* __restrict__ out) {
    __shared__ __align__(16) float lds[16 * HP];   // 16512 B

    const int b  = blockIdx.x;       // 0..16 row-block
    const int pi = blockIdx.y;       // plane index (B*12*C planes)
    const int face = (pi / NCH) % 12;
    const int t = threadIdx.x;

    const float* inp = in + (size_t)pi * FACE_ELEMS;
    const int oy0 = b * 16;

    if (b >= 1 && b < 16) {
        // 16 interior rows: input rows iy = oy0-1 .. oy0+14.
        // float4 loads: wave w, step k handles full input row (w + 4k);
        // lanes cover 64 consecutive float4 -> 1KB/instr coalesced.
        const int iy0 = oy0 - 1;
        #pragma unroll
        for (int k = 0; k < 4; ++k) {
            const int q = t + 256 * k;          // 0..1023
            const int row = q >> 6;             // 0..15
            const int c4  = q & 63;             // float4 index within row
            const float4 v = *reinterpret_cast<const float4*>(
                &inp[(iy0 + row) * HH + 4 * c4]);
            float* d = &lds[row * HP + 1 + 4 * c4];
            d[0] = v.x; d[1] = v.y; d[2] = v.z; d[3] = v.w;
        }
        if (t < 16)                     // left halo col
            lds[t * HP] = halo_val(in, pi, face, oy0 + t, 0);
        else if (t < 32) {              // right halo col
            const int r = t - 16;
            lds[r * HP + HP - 1] = halo_val(in, pi, face, oy0 + r, HP - 1);
        }
    } else if (b == 0) {
        // row 0 = top halo; rows 1..15 from input rows 0..14 (960 float4)
        #pragma unroll
        for (int k = 0; k < 4; ++k) {
            const int q = t + 256 * k;
            if (q < 15 * 64) {
                const int row = q >> 6;         // 0..14
                const int c4  = q & 63;
                const float4 v = *reinterpret_cast<const float4*>(
                    &inp[row * HH + 4 * c4]);
                float* d = &lds[(row + 1) * HP + 1 + 4 * c4];
                d[0] = v.x; d[1] = v.y; d[2] = v.z; d[3] = v.w;
            }
        }
        for (int ox = t; ox < HP; ox += 256)
            lds[ox] = halo_val(in, pi, face, 0, ox);
        if (t >= 1 && t < 16)           // left halo col, rows 1..15
            lds[t * HP] = halo_val(in, pi, face, t, 0);
        else if (t >= 17 && t < 32) {   // right halo col, rows 1..15
            const int r = t - 16;
            lds[r * HP + HP - 1] = halo_val(in, pi, face, r, HP - 1);
        }
    } else {
        // b == 16: row 256 (interior, iy=255) + row 257 (bottom halo)
        if (t < 64) {
            const float4 v = *reinterpret_cast<const float4*>(
                &inp[255 * HH + 4 * t]);
            float* d = &lds[1 + 4 * t];
            d[0] = v.x; d[1] = v.y; d[2] = v.z; d[3] = v.w;
        } else if (t == 64) {
            lds[0]      = halo_val(in, pi, face, 256, 0);
        } else if (t == 65) {
            lds[HP - 1] = halo_val(in, pi, face, 256, HP - 1);
        }
        for (int ox = t; ox < HP; ox += 256)
            lds[HP + ox] = halo_val(in, pi, face, 257, ox);
    }

    __syncthreads();

    // Aligned contiguous store: ds_read_b128 + global_store_dwordx4.
    const int n4 = (b < 16) ? (16 * HP / 4) : (2 * HP / 4);   // 1032 or 129
    float* outbase = out + (size_t)pi * OFACE_ELEMS + (size_t)oy0 * HP;
    for (int q = t; q < n4; q += 256) {
        const float4 v = *reinterpret_cast<const float4*>(&lds[4 * q]);
        *reinterpret_cast<float4*>(&outbase[4 * q]) = v;
    }
}

extern "C" void kernel_launch(void* const* d_in, const int* in_sizes, int n_in,
                              void* d_out, int out_size, void* d_ws, size_t ws_size,
                              hipStream_t stream) {
    const float* x = (const float*)d_in[0];
    float* out = (float*)d_out;

    const int P = in_sizes[0] / FACE_ELEMS;   // B*12*C = 1536 planes
    dim3 grid(17, P);
    healpix_fused<<<grid, 256, 0, stream>>>(x, out);
}